// Round 1
// baseline (169.093 us; speedup 1.0000x reference)
//
#include <hip/hip_runtime.h>
#include <cmath>

// ---- types -----------------------------------------------------------------
typedef float  f32x4  __attribute__((ext_vector_type(4)));
typedef __bf16 bf16x8 __attribute__((ext_vector_type(8)));
typedef __bf16 bf16x4 __attribute__((ext_vector_type(4)));
typedef __bf16 bf16x2 __attribute__((ext_vector_type(2)));

#define MFMA16(acc, a, b) (acc) = __builtin_amdgcn_mfma_f32_16x16x32_bf16((a), (b), (acc), 0, 0, 0)

// Geometry: x is [B=2, C=128, D=16, H=64, W=64] fp32.
// flat index = b*8388608 + c*65536 + d*4096 + hw
// tile = 128 consecutive hw positions of one (b,d) plane.

// LDS tile helper: [row][colByte] with pitch 256B, XOR swizzle (guide G4):
// keeps 16B-aligned reads conflict-light and is its own inverse.
__device__ __forceinline__ int swz(int row, int colByte){ return row*256 + (colByte ^ ((row & 7) << 4)); }
// 128B-pitch variant for the 32x64 k/v half tiles in K1.
__device__ __forceinline__ int swz128(int row, int colByte){ return row*128 + (colByte ^ ((row & 7) << 4)); }

// Load 8 consecutive fp32 weights -> bf16x8 A-fragment (global, L2-hot).
__device__ __forceinline__ bf16x8 ldw(const float* __restrict__ p){
  f32x4 a = *((const f32x4*)p);
  f32x4 b = *((const f32x4*)(p + 4));
  bf16x8 r;
  #pragma unroll
  for (int i = 0; i < 4; ++i){ r[i] = (__bf16)a[i]; r[i+4] = (__bf16)b[i]; }
  return r;
}

// Stage one 128pos x 128ch fp32 tile -> LDS bf16 [pos][c] (transposed, swizzled).
// Thread t loads channel pair (c, c+1) at position p = t&127 -> one b32 write.
__device__ __forceinline__ void stage_x(const float* __restrict__ xb, char* ldsX, int t){
  int p  = t & 127;
  int c0 = (t >> 7) * 2;         // 0 or 2
  const float* col = xb + p;
  #pragma unroll 8
  for (int i = 0; i < 32; ++i){
    int c = c0 + i * 4;
    float a = col[c * 65536];
    float b = col[(c + 1) * 65536];
    bf16x2 u; u[0] = (__bf16)a; u[1] = (__bf16)b;
    *(bf16x2*)(ldsX + swz(p, c * 2)) = u;
  }
}

// ---- K1: k/v projection + LayerNorm + kv partial accumulation --------------
// grid 512 = 32 bd-slices x 16 sub; each block: 2 tiles of 128 pos.
// wave w == head w. Writes part[bx][head][d][c] (fp32, transposed kv).
__global__ __launch_bounds__(256) void k1_kv(
    const float* __restrict__ x, const float* __restrict__ qkv_w, const float* __restrict__ qkv_b,
    const float* __restrict__ klw, const float* __restrict__ klb,
    const float* __restrict__ vlw, const float* __restrict__ vlb,
    float* __restrict__ part){
  __shared__ char lds[65536];
  char* ldsX = lds;
  int t = threadIdx.x;
  int lane = t & 63, w = t >> 6, l15 = lane & 15, l4 = lane >> 4;
  char* kst = lds + 32768 + w * 8192;   // wave-private [32][64] bf16 k half-tile
  char* vst = kst + 4096;               // v half-tile
  int bx = blockIdx.x;
  int bd = bx >> 4, sub = bx & 15;
  int b = bd >> 4, d = bd & 15;
  const float* xslice = x + b * 8388608 + d * 4096;
  // qkv channel map: head h occupies rows [96h,96h+96): q +0, k +32, v +64.
  int ko = 96 * w + 32, vo = 96 * w + 64;

  f32x4 kv[2][2] = {};   // accumulates across both tiles

  // per-lane LN params and biases (rows cc = 16*fm + l4*4 + r)
  f32x4 lwk[2], lbk[2], lwv[2], lbv[2], bk[2], bv[2];
  #pragma unroll
  for (int fm = 0; fm < 2; ++fm){
    int cc0 = 16 * fm + l4 * 4;
    lwk[fm] = *(const f32x4*)(klw + 32 * w + cc0);
    lbk[fm] = *(const f32x4*)(klb + 32 * w + cc0);
    lwv[fm] = *(const f32x4*)(vlw + 32 * w + cc0);
    lbv[fm] = *(const f32x4*)(vlb + 32 * w + cc0);
    bk[fm]  = *(const f32x4*)(qkv_b + ko + cc0);
    bv[fm]  = *(const f32x4*)(qkv_b + vo + cc0);
  }

  for (int ti = 0; ti < 2; ++ti){
    const float* xb = xslice + (sub * 2 + ti) * 128;
    __syncthreads();                 // protect X area from previous iteration readers
    stage_x(xb, ldsX, t);
    __syncthreads();

    // k,v = W_kv . x^T  (D[o][pos]); wave w: its head's 32 k-rows + 32 v-rows
    f32x4 ak[2][8] = {}, av[2][8] = {};
    for (int kf = 0; kf < 4; ++kf){
      bf16x8 bn[8];
      #pragma unroll
      for (int fn = 0; fn < 8; ++fn)
        bn[fn] = *(const bf16x8*)(ldsX + swz(16 * fn + l15, kf * 64 + l4 * 16));
      int cb = kf * 32 + l4 * 8;
      bf16x8 a_k0 = ldw(qkv_w + (ko + l15) * 128 + cb);
      bf16x8 a_k1 = ldw(qkv_w + (ko + 16 + l15) * 128 + cb);
      bf16x8 a_v0 = ldw(qkv_w + (vo + l15) * 128 + cb);
      bf16x8 a_v1 = ldw(qkv_w + (vo + 16 + l15) * 128 + cb);
      #pragma unroll
      for (int fn = 0; fn < 8; ++fn){
        MFMA16(ak[0][fn], a_k0, bn[fn]);
        MFMA16(ak[1][fn], a_k1, bn[fn]);
        MFMA16(av[0][fn], a_v0, bn[fn]);
        MFMA16(av[1][fn], a_v1, bn[fn]);
      }
    }

    // bias + LayerNorm over hc=32 per position (ddof=1, denom = std + eps)
    #pragma unroll
    for (int fn = 0; fn < 8; ++fn){
      float s1k = 0.f, s2k = 0.f, s1v = 0.f, s2v = 0.f;
      #pragma unroll
      for (int fm = 0; fm < 2; ++fm)
        #pragma unroll
        for (int r = 0; r < 4; ++r){
          float kk = ak[fm][fn][r] + bk[fm][r];
          float vv = av[fm][fn][r] + bv[fm][r];
          ak[fm][fn][r] = kk; av[fm][fn][r] = vv;
          s1k += kk; s2k += kk * kk;
          s1v += vv; s2v += vv * vv;
        }
      s1k += __shfl_xor(s1k, 16); s2k += __shfl_xor(s2k, 16);
      s1v += __shfl_xor(s1v, 16); s2v += __shfl_xor(s2v, 16);
      s1k += __shfl_xor(s1k, 32); s2k += __shfl_xor(s2k, 32);
      s1v += __shfl_xor(s1v, 32); s2v += __shfl_xor(s2v, 32);
      float mk = s1k * (1.f / 32.f), mv = s1v * (1.f / 32.f);
      float vark = fmaxf((s2k - 32.f * mk * mk) * (1.f / 31.f), 0.f);
      float varv = fmaxf((s2v - 32.f * mv * mv) * (1.f / 31.f), 0.f);
      float ik = 1.f / (sqrtf(vark) + 1e-5f);
      float iv = 1.f / (sqrtf(varv) + 1e-5f);
      #pragma unroll
      for (int fm = 0; fm < 2; ++fm)
        #pragma unroll
        for (int r = 0; r < 4; ++r){
          ak[fm][fn][r] = (ak[fm][fn][r] - mk) * ik * lwk[fm][r] + lbk[fm][r];
          av[fm][fn][r] = (av[fm][fn][r] - mv) * iv * lwv[fm][r] + lbv[fm][r];
        }
    }

    // kv[c][d] += sum_pos k[c,pos]*v[d,pos]: LDS round-trip (K=pos), half tiles
    for (int half = 0; half < 2; ++half){
      #pragma unroll
      for (int fn4 = 0; fn4 < 4; ++fn4){
        int fn = half * 4 + fn4;
        int pcol = 16 * fn4 + l15;     // 0..63 within half
        #pragma unroll
        for (int fm = 0; fm < 2; ++fm)
          #pragma unroll
          for (int r = 0; r < 4; ++r){
            int cc = 16 * fm + l4 * 4 + r;
            *(__bf16*)(kst + swz128(cc, pcol * 2)) = (__bf16)ak[fm][fn][r];
            *(__bf16*)(vst + swz128(cc, pcol * 2)) = (__bf16)av[fm][fn][r];
          }
      }
      __syncthreads();
      #pragma unroll
      for (int kf = 0; kf < 2; ++kf){
        bf16x8 am0 = *(const bf16x8*)(kst + swz128(l15,      kf * 64 + l4 * 16));
        bf16x8 am1 = *(const bf16x8*)(kst + swz128(16 + l15, kf * 64 + l4 * 16));
        bf16x8 bn0 = *(const bf16x8*)(vst + swz128(l15,      kf * 64 + l4 * 16));
        bf16x8 bn1 = *(const bf16x8*)(vst + swz128(16 + l15, kf * 64 + l4 * 16));
        MFMA16(kv[0][0], am0, bn0);
        MFMA16(kv[0][1], am0, bn1);
        MFMA16(kv[1][0], am1, bn0);
        MFMA16(kv[1][1], am1, bn1);
      }
      __syncthreads();
    }
  }

  // store partial transposed: part[bx][head][d][c] = kv[c][d]
  float* pb = part + ((size_t)bx * 4 + w) * 1024;
  #pragma unroll
  for (int fm = 0; fm < 2; ++fm)
    #pragma unroll
    for (int fn = 0; fn < 2; ++fn){
      int dcol = 16 * fn + l15;
      int c0   = 16 * fm + l4 * 4;
      *(f32x4*)(pb + dcol * 32 + c0) = kv[fm][fn];
    }
}

// ---- K1.5: reduce partials -> kv^T bf16 [bd][head][d][c], scaled 1/(H*W) ---
__global__ __launch_bounds__(256) void k15_reduce(const float* __restrict__ part,
                                                  __bf16* __restrict__ kvt){
  int bd = blockIdx.x, t = threadIdx.x;
  #pragma unroll
  for (int i = 0; i < 16; ++i){
    int e = i * 256 + t;
    float s = 0.f;
    #pragma unroll
    for (int sub = 0; sub < 16; ++sub)
      s += part[((size_t)(bd * 16 + sub)) * 4096 + e];
    kvt[bd * 4096 + e] = (__bf16)(s * (1.f / 4096.f));
  }
}

// ---- K2: q proj -> attention -> +x -> o1+gelu -> o2 + bias + x -------------
// grid 1024 (one 128-pos tile each), wave w == head w for q/attn, 64KiB LDS.
__global__ __launch_bounds__(256) void k2_main(
    const float* __restrict__ x, const float* __restrict__ qkv_w, const float* __restrict__ qkv_b,
    const float* __restrict__ o1w, const float* __restrict__ o1b,
    const float* __restrict__ o2w, const float* __restrict__ o2b,
    const __bf16* __restrict__ kvt, float* __restrict__ out){
  __shared__ char lds[65536];
  char* ldsX = lds;            // x tile, bf16 [pos][c] (also residual source)
  char* ldsQ = lds + 32768;    // q -> ret -> h (in-place reuse)
  int t = threadIdx.x;
  int lane = t & 63, w = t >> 6, l15 = lane & 15, l4 = lane >> 4;
  int bx = blockIdx.x;
  int bd = bx >> 5, hwt = bx & 31;
  int b = bd >> 4, d = bd & 15;
  const float* xb = x + b * 8388608 + d * 4096 + hwt * 128;
  float* ob = out + b * 8388608 + d * 4096 + hwt * 128;

  stage_x(xb, ldsX, t);
  __syncthreads();

  // ---- q projection: rows 96w..96w+31 of qkv_w, stored at channels 32w.. --
  {
    f32x4 acc[2][8] = {};
    int qo = 96 * w;
    for (int kf = 0; kf < 4; ++kf){
      bf16x8 bn[8];
      #pragma unroll
      for (int fn = 0; fn < 8; ++fn)
        bn[fn] = *(const bf16x8*)(ldsX + swz(16 * fn + l15, kf * 64 + l4 * 16));
      int cb = kf * 32 + l4 * 8;
      bf16x8 a0 = ldw(qkv_w + (qo + l15) * 128 + cb);
      bf16x8 a1 = ldw(qkv_w + (qo + 16 + l15) * 128 + cb);
      #pragma unroll
      for (int fn = 0; fn < 8; ++fn){
        MFMA16(acc[0][fn], a0, bn[fn]);
        MFMA16(acc[1][fn], a1, bn[fn]);
      }
    }
    #pragma unroll
    for (int fm = 0; fm < 2; ++fm){
      f32x4 qb = *(const f32x4*)(qkv_b + qo + 16 * fm + l4 * 4);
      int cq2 = (32 * w + 16 * fm + l4 * 4) * 2;
      #pragma unroll
      for (int fn = 0; fn < 8; ++fn){
        int pos = 16 * fn + l15;
        bf16x4 pk;
        #pragma unroll
        for (int r = 0; r < 4; ++r) pk[r] = (__bf16)(acc[fm][fn][r] + qb[r]);
        *(bf16x4*)(ldsQ + swz(pos, cq2)) = pk;
      }
    }
  }
  __syncthreads();

  // ---- attention: ret^T[d][pos] = kv^T . q^T, then += x (head-diagonal) ---
  {
    const __bf16* kvh = kvt + (bd * 4 + w) * 1024;
    bf16x8 ka0 = *(const bf16x8*)(kvh + l15 * 32 + l4 * 8);
    bf16x8 ka1 = *(const bf16x8*)(kvh + (16 + l15) * 32 + l4 * 8);
    f32x4 acc[2][8] = {};
    #pragma unroll
    for (int fn = 0; fn < 8; ++fn){
      bf16x8 bq = *(const bf16x8*)(ldsQ + swz(16 * fn + l15, 64 * w + l4 * 16));
      MFMA16(acc[0][fn], ka0, bq);
      MFMA16(acc[1][fn], ka1, bq);
    }
    #pragma unroll
    for (int fm = 0; fm < 2; ++fm){
      int oc2 = (32 * w + 16 * fm + l4 * 4) * 2;
      #pragma unroll
      for (int fn = 0; fn < 8; ++fn){
        int pos = 16 * fn + l15;
        bf16x4 xv = *(const bf16x4*)(ldsX + swz(pos, oc2));
        bf16x4 pk;
        #pragma unroll
        for (int r = 0; r < 4; ++r) pk[r] = (__bf16)(acc[fm][fn][r] + (float)xv[r]);
        *(bf16x4*)(ldsQ + swz(pos, oc2)) = pk;   // in-place: own head's columns
      }
    }
  }
  __syncthreads();   // all ret columns visible before o1 mixes channels

  int oo = 32 * w;
  // ---- o1 + exact gelu ----------------------------------------------------
  {
    f32x4 acc[2][8] = {};
    for (int kf = 0; kf < 4; ++kf){
      bf16x8 bn[8];
      #pragma unroll
      for (int fn = 0; fn < 8; ++fn)
        bn[fn] = *(const bf16x8*)(ldsQ + swz(16 * fn + l15, kf * 64 + l4 * 16));
      int cb = kf * 32 + l4 * 8;
      bf16x8 a0 = ldw(o1w + (oo + l15) * 128 + cb);
      bf16x8 a1 = ldw(o1w + (oo + 16 + l15) * 128 + cb);
      #pragma unroll
      for (int fn = 0; fn < 8; ++fn){
        MFMA16(acc[0][fn], a0, bn[fn]);
        MFMA16(acc[1][fn], a1, bn[fn]);
      }
    }
    __syncthreads();   // all waves done reading ret before h overwrites it
    #pragma unroll
    for (int fm = 0; fm < 2; ++fm){
      f32x4 bb = *(const f32x4*)(o1b + oo + 16 * fm + l4 * 4);
      int oc2 = (oo + 16 * fm + l4 * 4) * 2;
      #pragma unroll
      for (int fn = 0; fn < 8; ++fn){
        int pos = 16 * fn + l15;
        bf16x4 pk;
        #pragma unroll
        for (int r = 0; r < 4; ++r){
          float v = acc[fm][fn][r] + bb[r];
          v = 0.5f * v * (1.f + erff(v * 0.70710678118654752f));   // exact gelu
          pk[r] = (__bf16)v;
        }
        *(bf16x4*)(ldsQ + swz(pos, oc2)) = pk;
      }
    }
  }
  __syncthreads();

  // ---- o2 + bias + residual x, store fp32 ---------------------------------
  {
    f32x4 acc[2][8] = {};
    for (int kf = 0; kf < 4; ++kf){
      bf16x8 bn[8];
      #pragma unroll
      for (int fn = 0; fn < 8; ++fn)
        bn[fn] = *(const bf16x8*)(ldsQ + swz(16 * fn + l15, kf * 64 + l4 * 16));
      int cb = kf * 32 + l4 * 8;
      bf16x8 a0 = ldw(o2w + (oo + l15) * 128 + cb);
      bf16x8 a1 = ldw(o2w + (oo + 16 + l15) * 128 + cb);
      #pragma unroll
      for (int fn = 0; fn < 8; ++fn){
        MFMA16(acc[0][fn], a0, bn[fn]);
        MFMA16(acc[1][fn], a1, bn[fn]);
      }
    }
    #pragma unroll
    for (int fm = 0; fm < 2; ++fm){
      int o0 = oo + 16 * fm + l4 * 4;
      f32x4 bb = *(const f32x4*)(o2b + o0);
      #pragma unroll
      for (int fn = 0; fn < 8; ++fn){
        int pos = 16 * fn + l15;
        bf16x4 xv = *(const bf16x4*)(ldsX + swz(pos, o0 * 2));
        #pragma unroll
        for (int r = 0; r < 4; ++r)
          ob[(o0 + r) * 65536 + pos] = acc[fm][fn][r] + bb[r] + (float)xv[r];
      }
    }
  }
}

// ---- launch ----------------------------------------------------------------
extern "C" void kernel_launch(void* const* d_in, const int* in_sizes, int n_in,
                              void* d_out, int out_size, void* d_ws, size_t ws_size,
                              hipStream_t stream){
  const float* x     = (const float*)d_in[0];
  const float* qkv_w = (const float*)d_in[1];
  const float* qkv_b = (const float*)d_in[2];
  const float* o1w   = (const float*)d_in[3];
  const float* o1b   = (const float*)d_in[4];
  const float* o2w   = (const float*)d_in[5];
  const float* o2b   = (const float*)d_in[6];
  const float* klw   = (const float*)d_in[7];
  const float* klb   = (const float*)d_in[8];
  const float* vlw   = (const float*)d_in[9];
  const float* vlb   = (const float*)d_in[10];

  float*  part = (float*)d_ws;                                   // 512*4096*4 = 8 MiB
  __bf16* kvt  = (__bf16*)((char*)d_ws + (size_t)512 * 4096 * 4); // 32*4096*2 = 256 KiB

  k1_kv<<<512, 256, 0, stream>>>(x, qkv_w, qkv_b, klw, klb, vlw, vlb, part);
  k15_reduce<<<32, 256, 0, stream>>>(part, kvt);
  k2_main<<<1024, 256, 0, stream>>>(x, qkv_w, qkv_b, o1w, o1b, o2w, o2b, kvt, (float*)d_out);
}

// Round 2
// 136.153 us; speedup vs baseline: 1.2419x; 1.2419x over previous
//
#include <hip/hip_runtime.h>
#include <cmath>

// ---- types -----------------------------------------------------------------
typedef float  f32x4  __attribute__((ext_vector_type(4)));
typedef __bf16 bf16x8 __attribute__((ext_vector_type(8)));
typedef __bf16 bf16x4 __attribute__((ext_vector_type(4)));
typedef __bf16 bf16x2 __attribute__((ext_vector_type(2)));

#define MFMA16(acc, a, b) (acc) = __builtin_amdgcn_mfma_f32_16x16x32_bf16((a), (b), (acc), 0, 0, 0)

// Geometry: x is [B=2, C=128, D=16, H=64, W=64] fp32.
// flat = b*8388608 + c*65536 + d*4096 + hw.  Tile = 64 consecutive hw.

// LDS [row][colByte], pitch 256B (x tiles, 64 rows) / 128B (k/v, 128 rows).
// XOR swizzle keeps 16B reads conflict-free (guide G4 / T2).
__device__ __forceinline__ int swz(int row, int colByte){ return row*256 + (colByte ^ ((row & 7) << 4)); }
__device__ __forceinline__ int swz128(int row, int colByte){ return row*128 + (colByte ^ ((row & 7) << 4)); }

// 8 consecutive fp32 weights -> bf16x8 A-fragment (global, L2-hot).
__device__ __forceinline__ bf16x8 ldw(const float* __restrict__ p){
  f32x4 a = *((const f32x4*)p);
  f32x4 b = *((const f32x4*)(p + 4));
  bf16x8 r;
  #pragma unroll
  for (int i = 0; i < 4; ++i){ r[i] = (__bf16)a[i]; r[i+4] = (__bf16)b[i]; }
  return r;
}

// Stage 64pos x 128ch fp32 -> LDS bf16 [pos][c] (transposed, swizzled).
// Thread t: pos p = t&63, 8-channel group per iter -> one b128 write
// (8 lanes per 4-bank group = conflict-free; loads coalesced 256B/wave).
__device__ __forceinline__ void stage_x64(const float* __restrict__ xb, char* ldsX, int t){
  int p  = t & 63;
  int cg = t >> 6;               // 0..3
  const float* col = xb + p;
  #pragma unroll
  for (int i = 0; i < 4; ++i){
    int c = cg * 8 + i * 32;
    bf16x8 u;
    #pragma unroll
    for (int j = 0; j < 8; ++j) u[j] = (__bf16)col[(c + j) * 65536];
    *(bf16x8*)(ldsX + swz(p, c * 2)) = u;
  }
}

// ---- K1: k/v projection + LayerNorm + kv partial accumulation --------------
// grid 1024 = 32 bd x 32 sub; block 256 (wave = head); one 128-pos tile as
// two 64-pos chunks. LDS 32KiB: [0,16K) x-tile then v-stage (overlaid),
// [16K,32K) k-stage. Sequential k/v projection reuses one accumulator.
__global__ __launch_bounds__(256) void k1_kv(
    const float* __restrict__ x, const float* __restrict__ qkv_w, const float* __restrict__ qkv_b,
    const float* __restrict__ klw, const float* __restrict__ klb,
    const float* __restrict__ vlw, const float* __restrict__ vlb,
    __bf16* __restrict__ part){
  __shared__ char lds[32768];
  char* ldsX = lds;            // x [64][256B]  -> later v [128][128B]
  char* ldsK = lds + 16384;    // k [128][128B]
  int t = threadIdx.x;
  int lane = t & 63, w = t >> 6, l15 = lane & 15, l4 = lane >> 4;
  int bx = blockIdx.x;
  int bd = bx >> 5, sub = bx & 31;
  int b = bd >> 4, d = bd & 15;
  const float* xslice = x + (size_t)b * 8388608 + d * 4096 + sub * 128;

  f32x4 kv[2][2] = {};   // accumulates across chunks

  for (int ch = 0; ch < 2; ++ch){
    __syncthreads();                       // prev chunk's outer-product reads done
    stage_x64(xslice + ch * 64, ldsX, t);
    __syncthreads();

    // phase 0: k (rows 96w+32..), phase 1: v (rows 96w+64..)
    #pragma unroll
    for (int ph = 0; ph < 2; ++ph){
      int po = 96 * w + 32 + 32 * ph;
      f32x4 acc[2][4] = {};
      for (int kf = 0; kf < 4; ++kf){
        bf16x8 bn[4];
        #pragma unroll
        for (int fn = 0; fn < 4; ++fn)
          bn[fn] = *(const bf16x8*)(ldsX + swz(16 * fn + l15, kf * 64 + l4 * 16));
        bf16x8 a0 = ldw(qkv_w + (po + l15) * 128 + kf * 32 + l4 * 8);
        bf16x8 a1 = ldw(qkv_w + (po + 16 + l15) * 128 + kf * 32 + l4 * 8);
        #pragma unroll
        for (int fn = 0; fn < 4; ++fn){
          MFMA16(acc[0][fn], a0, bn[fn]);
          MFMA16(acc[1][fn], a1, bn[fn]);
        }
      }
      // bias + LayerNorm over hc=32 per position (ddof=1, denom = std+eps)
      const float* lwp = (ph ? vlw : klw) + 32 * w;
      const float* lbp = (ph ? vlb : klb) + 32 * w;
      f32x4 bias0 = *(const f32x4*)(qkv_b + po + l4 * 4);
      f32x4 bias1 = *(const f32x4*)(qkv_b + po + 16 + l4 * 4);
      f32x4 lw0 = *(const f32x4*)(lwp + l4 * 4), lw1 = *(const f32x4*)(lwp + 16 + l4 * 4);
      f32x4 lb0 = *(const f32x4*)(lbp + l4 * 4), lb1 = *(const f32x4*)(lbp + 16 + l4 * 4);
      #pragma unroll
      for (int fn = 0; fn < 4; ++fn){
        f32x4 v0 = acc[0][fn] + bias0;
        f32x4 v1 = acc[1][fn] + bias1;
        float s1 = v0[0]+v0[1]+v0[2]+v0[3] + v1[0]+v1[1]+v1[2]+v1[3];
        float s2 = v0[0]*v0[0]+v0[1]*v0[1]+v0[2]*v0[2]+v0[3]*v0[3]
                 + v1[0]*v1[0]+v1[1]*v1[1]+v1[2]*v1[2]+v1[3]*v1[3];
        s1 += __shfl_xor(s1, 16); s2 += __shfl_xor(s2, 16);
        s1 += __shfl_xor(s1, 32); s2 += __shfl_xor(s2, 32);
        float m  = s1 * (1.f / 32.f);
        float var = fmaxf((s2 - 32.f * m * m) * (1.f / 31.f), 0.f);
        float inv = 1.f / (sqrtf(var) + 1e-5f);
        acc[0][fn] = (v0 - m) * inv * lw0 + lb0;
        acc[1][fn] = (v1 - m) * inv * lw1 + lb1;
      }
      if (ph == 1) __syncthreads();        // all waves done reading x before v overlays it
      char* dst = ph ? ldsX : ldsK;        // [128 ch][64 pos] bf16, swizzled
      #pragma unroll
      for (int fm = 0; fm < 2; ++fm)
        #pragma unroll
        for (int fn = 0; fn < 4; ++fn)
          #pragma unroll
          for (int r = 0; r < 4; ++r)
            *(__bf16*)(dst + swz128(32 * w + 16 * fm + l4 * 4 + r, (16 * fn + l15) * 2)) =
                (__bf16)acc[fm][fn][r];
    }

    // outer product kv[c][d] += sum_pos k[c,pos] v[d,pos]  (wave-private rows)
    #pragma unroll
    for (int kf = 0; kf < 2; ++kf){
      bf16x8 am0 = *(const bf16x8*)(ldsK + swz128(32 * w + l15,      kf * 64 + l4 * 16));
      bf16x8 am1 = *(const bf16x8*)(ldsK + swz128(32 * w + 16 + l15, kf * 64 + l4 * 16));
      bf16x8 bn0 = *(const bf16x8*)(ldsX + swz128(32 * w + l15,      kf * 64 + l4 * 16));
      bf16x8 bn1 = *(const bf16x8*)(ldsX + swz128(32 * w + 16 + l15, kf * 64 + l4 * 16));
      MFMA16(kv[0][0], am0, bn0);
      MFMA16(kv[0][1], am0, bn1);
      MFMA16(kv[1][0], am1, bn0);
      MFMA16(kv[1][1], am1, bn1);
    }
  }

  // store partial transposed bf16: part[bx][head][d][c] = kv[c][d]
  __bf16* pb = part + ((size_t)bx * 4 + w) * 1024;
  #pragma unroll
  for (int fm = 0; fm < 2; ++fm)
    #pragma unroll
    for (int fn = 0; fn < 2; ++fn){
      int dcol = 16 * fn + l15;
      int c0   = 16 * fm + l4 * 4;
      bf16x4 pk;
      #pragma unroll
      for (int r = 0; r < 4; ++r) pk[r] = (__bf16)kv[fm][fn][r];
      *(bf16x4*)(pb + dcol * 32 + c0) = pk;
    }
}

// ---- K1.5: reduce 32 bf16 partials -> kv^T bf16 [bd][head][d][c], /4096 ----
__global__ __launch_bounds__(256) void k15_reduce(const __bf16* __restrict__ part,
                                                  __bf16* __restrict__ kvt){
  int bx = blockIdx.x, t = threadIdx.x;
  int bd = bx >> 3, seg = bx & 7;
  int e = seg * 512 + t * 2;
  float s0 = 0.f, s1 = 0.f;
  #pragma unroll
  for (int sub = 0; sub < 32; ++sub){
    bf16x2 p = *(const bf16x2*)(part + (size_t)(bd * 32 + sub) * 4096 + e);
    s0 += (float)p[0]; s1 += (float)p[1];
  }
  bf16x2 o; o[0] = (__bf16)(s0 * (1.f / 4096.f)); o[1] = (__bf16)(s1 * (1.f / 4096.f));
  *(bf16x2*)(kvt + bd * 4096 + e) = o;
}

// ---- K2: q proj -> attention -> +x -> o1+gelu -> o2 + bias + x -------------
// grid 2048 (one 64-pos tile each), block 256 (wave = head), LDS 32KiB.
__global__ __launch_bounds__(256) void k2_main(
    const float* __restrict__ x, const float* __restrict__ qkv_w, const float* __restrict__ qkv_b,
    const float* __restrict__ o1w, const float* __restrict__ o1b,
    const float* __restrict__ o2w, const float* __restrict__ o2b,
    const __bf16* __restrict__ kvt, float* __restrict__ out){
  __shared__ char lds[32768];
  char* ldsX = lds;            // x tile bf16 [64][256B] (residual source, persists)
  char* ldsQ = lds + 16384;    // q -> ret -> h (in-place reuse)
  int t = threadIdx.x;
  int lane = t & 63, w = t >> 6, l15 = lane & 15, l4 = lane >> 4;
  int bx = blockIdx.x;
  int bd = bx >> 6, hwt = bx & 63;
  int b = bd >> 4, d = bd & 15;
  const float* xb = x + (size_t)b * 8388608 + d * 4096 + hwt * 64;
  float* ob = out + (size_t)b * 8388608 + d * 4096 + hwt * 64;

  stage_x64(xb, ldsX, t);
  __syncthreads();                                   // S1

  // ---- q projection (rows 96w..96w+31) -> ldsQ cols 32w.. (wave-private) --
  int qo = 96 * w, oo = 32 * w;
  {
    f32x4 acc[2][4] = {};
    for (int kf = 0; kf < 4; ++kf){
      bf16x8 bn[4];
      #pragma unroll
      for (int fn = 0; fn < 4; ++fn)
        bn[fn] = *(const bf16x8*)(ldsX + swz(16 * fn + l15, kf * 64 + l4 * 16));
      bf16x8 a0 = ldw(qkv_w + (qo + l15) * 128 + kf * 32 + l4 * 8);
      bf16x8 a1 = ldw(qkv_w + (qo + 16 + l15) * 128 + kf * 32 + l4 * 8);
      #pragma unroll
      for (int fn = 0; fn < 4; ++fn){
        MFMA16(acc[0][fn], a0, bn[fn]);
        MFMA16(acc[1][fn], a1, bn[fn]);
      }
    }
    #pragma unroll
    for (int fm = 0; fm < 2; ++fm){
      f32x4 qb = *(const f32x4*)(qkv_b + qo + 16 * fm + l4 * 4);
      int cq2 = (oo + 16 * fm + l4 * 4) * 2;
      #pragma unroll
      for (int fn = 0; fn < 4; ++fn){
        int pos = 16 * fn + l15;
        bf16x4 pk;
        #pragma unroll
        for (int r = 0; r < 4; ++r) pk[r] = (__bf16)(acc[fm][fn][r] + qb[r]);
        *(bf16x4*)(ldsQ + swz(pos, cq2)) = pk;
      }
    }
  }
  // no barrier: attention reads only head w's own columns (same wave wrote them)

  // ---- attention: ret^T[d][pos] = kv^T . q^T, += x residual, in place ----
  {
    const __bf16* kvh = kvt + (bd * 4 + w) * 1024;
    bf16x8 ka0 = *(const bf16x8*)(kvh + l15 * 32 + l4 * 8);
    bf16x8 ka1 = *(const bf16x8*)(kvh + (16 + l15) * 32 + l4 * 8);
    f32x4 acc[2][4] = {};
    #pragma unroll
    for (int fn = 0; fn < 4; ++fn){
      bf16x8 bq = *(const bf16x8*)(ldsQ + swz(16 * fn + l15, 64 * w + l4 * 16));
      MFMA16(acc[0][fn], ka0, bq);
      MFMA16(acc[1][fn], ka1, bq);
    }
    #pragma unroll
    for (int fm = 0; fm < 2; ++fm){
      int oc2 = (oo + 16 * fm + l4 * 4) * 2;
      #pragma unroll
      for (int fn = 0; fn < 4; ++fn){
        int pos = 16 * fn + l15;
        bf16x4 xv = *(const bf16x4*)(ldsX + swz(pos, oc2));
        bf16x4 pk;
        #pragma unroll
        for (int r = 0; r < 4; ++r) pk[r] = (__bf16)(acc[fm][fn][r] + (float)xv[r]);
        *(bf16x4*)(ldsQ + swz(pos, oc2)) = pk;
      }
    }
  }
  __syncthreads();                                   // S2: ret fully visible

  // ---- o1 + exact gelu ----------------------------------------------------
  {
    f32x4 acc[2][4] = {};
    for (int kf = 0; kf < 4; ++kf){
      bf16x8 bn[4];
      #pragma unroll
      for (int fn = 0; fn < 4; ++fn)
        bn[fn] = *(const bf16x8*)(ldsQ + swz(16 * fn + l15, kf * 64 + l4 * 16));
      bf16x8 a0 = ldw(o1w + (oo + l15) * 128 + kf * 32 + l4 * 8);
      bf16x8 a1 = ldw(o1w + (oo + 16 + l15) * 128 + kf * 32 + l4 * 8);
      #pragma unroll
      for (int fn = 0; fn < 4; ++fn){
        MFMA16(acc[0][fn], a0, bn[fn]);
        MFMA16(acc[1][fn], a1, bn[fn]);
      }
    }
    __syncthreads();                                 // S3: all ret reads done
    #pragma unroll
    for (int fm = 0; fm < 2; ++fm){
      f32x4 bb = *(const f32x4*)(o1b + oo + 16 * fm + l4 * 4);
      int oc2 = (oo + 16 * fm + l4 * 4) * 2;
      #pragma unroll
      for (int fn = 0; fn < 4; ++fn){
        int pos = 16 * fn + l15;
        bf16x4 pk;
        #pragma unroll
        for (int r = 0; r < 4; ++r){
          float v = acc[fm][fn][r] + bb[r];
          v = 0.5f * v * (1.f + erff(v * 0.70710678118654752f));   // exact gelu
          pk[r] = (__bf16)v;
        }
        *(bf16x4*)(ldsQ + swz(pos, oc2)) = pk;
      }
    }
  }
  __syncthreads();                                   // S4: h fully visible

  // ---- o2 + bias + residual x, store fp32 ---------------------------------
  {
    f32x4 acc[2][4] = {};
    for (int kf = 0; kf < 4; ++kf){
      bf16x8 bn[4];
      #pragma unroll
      for (int fn = 0; fn < 4; ++fn)
        bn[fn] = *(const bf16x8*)(ldsQ + swz(16 * fn + l15, kf * 64 + l4 * 16));
      bf16x8 a0 = ldw(o2w + (oo + l15) * 128 + kf * 32 + l4 * 8);
      bf16x8 a1 = ldw(o2w + (oo + 16 + l15) * 128 + kf * 32 + l4 * 8);
      #pragma unroll
      for (int fn = 0; fn < 4; ++fn){
        MFMA16(acc[0][fn], a0, bn[fn]);
        MFMA16(acc[1][fn], a1, bn[fn]);
      }
    }
    #pragma unroll
    for (int fm = 0; fm < 2; ++fm){
      int o0 = oo + 16 * fm + l4 * 4;
      f32x4 bb = *(const f32x4*)(o2b + o0);
      #pragma unroll
      for (int fn = 0; fn < 4; ++fn){
        int pos = 16 * fn + l15;
        bf16x4 xv = *(const bf16x4*)(ldsX + swz(pos, o0 * 2));
        #pragma unroll
        for (int r = 0; r < 4; ++r)
          ob[(size_t)(o0 + r) * 65536 + pos] = acc[fm][fn][r] + bb[r] + (float)xv[r];
      }
    }
  }
}

// ---- launch ----------------------------------------------------------------
extern "C" void kernel_launch(void* const* d_in, const int* in_sizes, int n_in,
                              void* d_out, int out_size, void* d_ws, size_t ws_size,
                              hipStream_t stream){
  const float* x     = (const float*)d_in[0];
  const float* qkv_w = (const float*)d_in[1];
  const float* qkv_b = (const float*)d_in[2];
  const float* o1w   = (const float*)d_in[3];
  const float* o1b   = (const float*)d_in[4];
  const float* o2w   = (const float*)d_in[5];
  const float* o2b   = (const float*)d_in[6];
  const float* klw   = (const float*)d_in[7];
  const float* klb   = (const float*)d_in[8];
  const float* vlw   = (const float*)d_in[9];
  const float* vlb   = (const float*)d_in[10];

  __bf16* part = (__bf16*)d_ws;                                    // 1024*4096*2 = 8 MiB
  __bf16* kvt  = (__bf16*)((char*)d_ws + (size_t)1024 * 4096 * 2); // 32*4096*2 = 256 KiB

  k1_kv<<<1024, 256, 0, stream>>>(x, qkv_w, qkv_b, klw, klb, vlw, vlb, part);
  k15_reduce<<<256, 256, 0, stream>>>(part, kvt);
  k2_main<<<2048, 256, 0, stream>>>(x, qkv_w, qkv_b, o1w, o1b, o2w, o2b, kvt, (float*)d_out);
}